// Round 2
// baseline (1104.886 us; speedup 1.0000x reference)
//
#include <hip/hip_runtime.h>
#include <hip/hip_bf16.h>

typedef __attribute__((ext_vector_type(8))) short short8;
typedef __attribute__((ext_vector_type(4))) float f32x4;

__device__ __forceinline__ short f2bfbits(float f) {
  union { __hip_bfloat16 h; short s; } cvt;
  cvt.h = __float2bfloat16(f);
  return cvt.s;
}
__device__ __forceinline__ float bfbits2f(short bits) {
  union { unsigned int u; float f; } cvt;
  cvt.u = ((unsigned int)(unsigned short)bits) << 16;
  return cvt.f;
}

// Async global->LDS, 16 B per lane. LDS dest = wave-uniform base + lane*16.
__device__ __forceinline__ void gl_lds16(const short* g, short* l) {
  __builtin_amdgcn_global_load_lds(
      (__attribute__((address_space(1))) void*)(g),
      (__attribute__((address_space(3))) void*)(l), 16, 0, 0);
}

// ---------------- fp32 -> bf16 weight conversion ----------
__global__ __launch_bounds__(256)
void f2bf(const float* __restrict__ s, short* __restrict__ d, int n) {
  const int i = (blockIdx.x * 256 + threadIdx.x) * 4;
  if (i >= n) return;
  float4 v = *(const float4*)(s + i);
  short o[4] = {f2bfbits(v.x), f2bfbits(v.y), f2bfbits(v.z), f2bfbits(v.w)};
  *(uint2*)(d + i) = *(const uint2*)o;
}

// ---------------- combined rel-pos-bias + shift-mask table: bm[wi][h][m][n] bf16
__global__ __launch_bounds__(256)
void bm_build(const float* __restrict__ table, const int* __restrict__ idx,
              const float* __restrict__ mask, short* __restrict__ bm) {
  const int wi = blockIdx.x, hh = blockIdx.y;
  const int n = threadIdx.x & 63;
  const int m0 = (threadIdx.x >> 6) * 16;
#pragma unroll
  for (int mm = 0; mm < 16; mm++) {
    const int m = m0 + mm;
    const float t = table[idx[m * 64 + n] * 16 + hh];
    const float mk = mask[wi * 4096 + m * 64 + n];
    bm[((long)(wi * 16 + hh) * 64 + m) * 64 + n] = f2bfbits(t + mk);
  }
}

// ---------------- LN1 + roll(-4,-4) + window partition (fp32 in, bf16 out) --
__global__ __launch_bounds__(256)
void ln1_win(const float* __restrict__ x, const float* __restrict__ w,
             const float* __restrict__ b, short* __restrict__ h) {
  const int lane = threadIdx.x & 63;
  const int wv = threadIdx.x >> 6;
  const int t = blockIdx.x * 4 + wv;
  const int n = t & 63, wiB = t >> 6;
  const int wi = wiB & 63, bb = wiB >> 6;
  const int sr = (((wi >> 3) << 3) + (n >> 3) + 4) & 63;
  const int sc = (((wi & 7) << 3) + (n & 7) + 4) & 63;
  const float* xp = x + ((long)bb * 4096 + sr * 64 + sc) * 512 + lane * 8;
  float4 u0 = *(const float4*)(xp);
  float4 u1 = *(const float4*)(xp + 4);
  float v[8] = {u0.x, u0.y, u0.z, u0.w, u1.x, u1.y, u1.z, u1.w};
  float s = 0.f;
#pragma unroll
  for (int j = 0; j < 8; j++) s += v[j];
#pragma unroll
  for (int o = 1; o < 64; o <<= 1) s += __shfl_xor(s, o, 64);
  const float mean = s * (1.0f / 512.0f);
  float q = 0.f;
#pragma unroll
  for (int j = 0; j < 8; j++) { float d = v[j] - mean; q += d * d; }
#pragma unroll
  for (int o = 1; o < 64; o <<= 1) q += __shfl_xor(q, o, 64);
  const float rstd = rsqrtf(q * (1.0f / 512.0f) + 1e-5f);
  float4 w0 = *(const float4*)(w + lane * 8);
  float4 w1 = *(const float4*)(w + lane * 8 + 4);
  float4 b0 = *(const float4*)(b + lane * 8);
  float4 b1 = *(const float4*)(b + lane * 8 + 4);
  const float wv8[8] = {w0.x, w0.y, w0.z, w0.w, w1.x, w1.y, w1.z, w1.w};
  const float bv8[8] = {b0.x, b0.y, b0.z, b0.w, b1.x, b1.y, b1.z, b1.w};
  short outs[8];
#pragma unroll
  for (int j = 0; j < 8; j++)
    outs[j] = f2bfbits((v[j] - mean) * rstd * wv8[j] + bv8[j]);
  *(uint4*)(h + (long)t * 512 + lane * 8) = *(const uint4*)outs;
}

// ---------------- LN2 (identity layout, fp32 in, bf16 out) ----------------
__global__ __launch_bounds__(256)
void ln2_id(const float* __restrict__ x2, const float* __restrict__ w,
            const float* __restrict__ b, short* __restrict__ out) {
  const int lane = threadIdx.x & 63;
  const int wv = threadIdx.x >> 6;
  const long t = blockIdx.x * 4 + wv;
  const float* xp = x2 + t * 512 + lane * 8;
  float4 u0 = *(const float4*)(xp);
  float4 u1 = *(const float4*)(xp + 4);
  float v[8] = {u0.x, u0.y, u0.z, u0.w, u1.x, u1.y, u1.z, u1.w};
  float s = 0.f;
#pragma unroll
  for (int j = 0; j < 8; j++) s += v[j];
#pragma unroll
  for (int o = 1; o < 64; o <<= 1) s += __shfl_xor(s, o, 64);
  const float mean = s * (1.0f / 512.0f);
  float q = 0.f;
#pragma unroll
  for (int j = 0; j < 8; j++) { float d = v[j] - mean; q += d * d; }
#pragma unroll
  for (int o = 1; o < 64; o <<= 1) q += __shfl_xor(q, o, 64);
  const float rstd = rsqrtf(q * (1.0f / 512.0f) + 1e-5f);
  float4 w0 = *(const float4*)(w + lane * 8);
  float4 w1 = *(const float4*)(w + lane * 8 + 4);
  float4 b0 = *(const float4*)(b + lane * 8);
  float4 b1 = *(const float4*)(b + lane * 8 + 4);
  const float wv8[8] = {w0.x, w0.y, w0.z, w0.w, w1.x, w1.y, w1.z, w1.w};
  const float bv8[8] = {b0.x, b0.y, b0.z, b0.w, b1.x, b1.y, b1.z, b1.w};
  short outs[8];
#pragma unroll
  for (int j = 0; j < 8; j++)
    outs[j] = f2bfbits((v[j] - mean) * rstd * wv8[j] + bv8[j]);
  *(uint4*)(out + t * 512 + lane * 8) = *(const uint4*)outs;
}

// ---------------- persistent 256x256 8-phase B^T GEMM ----------------------
// out[M,N] = A[M,K] @ Bw[N,K]^T + epilogue.  512 threads = 8 waves (2M x 4N),
// per-wave 128x64 output, BK=64, double-buffered LDS (128 KiB), staging via
// global_load_lds w/ pre-swizzled source (granule ^= row&7), counted vmcnt(8).
// Each block processes MTB consecutive M-tiles in one N-column: the K-loop is
// linearized across M-tiles (t+2 prefetch crosses the boundary), so pipeline
// fill/drain happens once per block and the epilogue overlaps the next
// M-tile's staging. Epilogue stores are older than the in-flight stage loads
// at every subsequent vmcnt(8), so the counted-wait discipline is preserved.
// MODE 0: +bias -> Q/K to qk (stride 1024); V third transposed to out2 vT
// MODE 1: +bias, window-reverse + roll(+4) scatter, + residual aux -> fp32
// MODE 2: +bias, exact GELU -> bf16
// MODE 3: +bias, + residual aux (fp32, row-major) -> fp32 (final out)
template <int MODE, int K, int GN, int MTB>
__global__ __launch_bounds__(512, 2)
void gemm256(const short* __restrict__ A, const short* __restrict__ Bw,
             const float* __restrict__ bias, const float* __restrict__ aux,
             void* __restrict__ outv, short* __restrict__ out2) {
  __shared__ short lds[65536];  // [2][16384] A tiles, then [2][16384] B tiles
  constexpr int NT = K / 64;
  constexpr int LNT = (NT == 8) ? 3 : (NT == 16 ? 4 : 5);
  constexpr int TOT = MTB * NT;
  const int tid = threadIdx.x;
  const int lane = tid & 63, wave = tid >> 6;
  const int l15 = lane & 15, quad = lane >> 4;
  const int wr = wave >> 2, wc = wave & 3;

  // XCD-chunked bijective swizzle (grid always a multiple of 8 here).
  const int nwg = gridDim.x;
  const int chunk = nwg >> 3;
  const int wg = (blockIdx.x & 7) * chunk + (blockIdx.x >> 3);
  const int row0 = (wg / GN) * (256 * MTB);   // first M-tile row of this block
  const int col0 = (wg % GN) * 256;

  // staging source (pre-swizzled): LDS slot (row, g) holds global (row, g^(row&7))
  const int srow = lane >> 3;                 // = row & 7 for this lane's rows
  const int scol = ((lane & 7) ^ srow) * 8;   // swizzled source granule (shorts)
  const short* Ag = A + (long)(row0 + wave * 8 + srow) * K + scol;
  const short* Bg = Bw + (long)(col0 + wave * 8 + srow) * K + scol;
  short* ldsAw = lds + wave * 512;            // + lane*16B added by HW
  short* ldsBw = lds + 32768 + wave * 512;

  // LDS read bases: logical granule (ks*4+quad) -> fetch granule ^ (row&7)
  const int g0 = (quad ^ (l15 & 7)) * 8;          // ks=0
  const int g1 = ((quad ^ 4) ^ (l15 & 7)) * 8;    // ks=1
  const int aB0 = (wr * 128 + l15) * 64 + g0;
  const int aB1 = (wr * 128 + l15) * 64 + g1;
  const int bB0 = 32768 + (wc * 64 + l15) * 64 + g0;
  const int bB1 = 32768 + (wc * 64 + l15) * 64 + g1;

  f32x4 acc[8][4];
#pragma unroll
  for (int m = 0; m < 8; m++)
#pragma unroll
    for (int n = 0; n < 4; n++) acc[m][n] = (f32x4){0.f, 0.f, 0.f, 0.f};

  // linear tile index kt -> (M-tile kt>>LNT, k-step kt&(NT-1))
#define STAGE(cOff, kt)                                                     \
  {                                                                         \
    const short* a_ = Ag + (long)((kt) >> LNT) * (256 * K) +                \
                      ((kt) & (NT - 1)) * 64;                               \
    const short* b_ = Bg + ((kt) & (NT - 1)) * 64;                          \
    _Pragma("unroll") for (int i_ = 0; i_ < 4; i_++) {                      \
      gl_lds16(a_ + (long)i_ * 64 * K, ldsAw + (cOff) + i_ * 4096);         \
      gl_lds16(b_ + (long)i_ * 64 * K, ldsBw + (cOff) + i_ * 4096);         \
    }                                                                       \
  }

  STAGE(0, 0);
  STAGE(16384, 1);
  asm volatile("s_waitcnt vmcnt(8)" ::: "memory");  // tile0 landed, tile1 in flight
  __builtin_amdgcn_s_barrier();

  for (int t = 0; t < TOT; ++t) {
    const int c = (t & 1) << 14;  // buffer offset in shorts
    const short* pa0 = lds + c + aB0;
    const short* pa1 = lds + c + aB1;
    const short* pb0 = lds + c + bB0;
    const short* pb1 = lds + c + bB1;
    short8 B0[4], B1[4], A0[4], A1[4], A2[4], A3[4];

    // -- phase 1: read B@ks0 + A[m0-3]@ks0; mfma(m0-3, ks0)
#pragma unroll
    for (int n = 0; n < 4; n++) B0[n] = *(const short8*)(pb0 + n * 1024);
#pragma unroll
    for (int m = 0; m < 4; m++) A0[m] = *(const short8*)(pa0 + m * 1024);
    asm volatile("" ::: "memory");
    __builtin_amdgcn_s_barrier();
    __builtin_amdgcn_s_setprio(1);
#pragma unroll
    for (int m = 0; m < 4; m++)
#pragma unroll
      for (int n = 0; n < 4; n++)
        acc[m][n] = __builtin_amdgcn_mfma_f32_16x16x32_bf16(A0[m], B0[n], acc[m][n], 0, 0, 0);
    __builtin_amdgcn_s_setprio(0);
    __builtin_amdgcn_s_barrier();

    // -- phase 2: read A[m4-7]@ks0 + B@ks1; mfma(m4-7, ks0)
#pragma unroll
    for (int m = 0; m < 4; m++) A1[m] = *(const short8*)(pa0 + (m + 4) * 1024);
#pragma unroll
    for (int n = 0; n < 4; n++) B1[n] = *(const short8*)(pb1 + n * 1024);
    asm volatile("" ::: "memory");
    __builtin_amdgcn_s_barrier();
    __builtin_amdgcn_s_setprio(1);
#pragma unroll
    for (int m = 0; m < 4; m++)
#pragma unroll
      for (int n = 0; n < 4; n++)
        acc[m + 4][n] = __builtin_amdgcn_mfma_f32_16x16x32_bf16(A1[m], B0[n], acc[m + 4][n], 0, 0, 0);
    __builtin_amdgcn_s_setprio(0);
    __builtin_amdgcn_s_barrier();

    // -- phase 3: read A[m0-3]@ks1 + A[m4-7]@ks1; mfma(m0-3, ks1); drain LDS
#pragma unroll
    for (int m = 0; m < 4; m++) A2[m] = *(const short8*)(pa1 + m * 1024);
#pragma unroll
    for (int m = 0; m < 4; m++) A3[m] = *(const short8*)(pa1 + (m + 4) * 1024);
    asm volatile("" ::: "memory");
    __builtin_amdgcn_s_barrier();
    __builtin_amdgcn_s_setprio(1);
#pragma unroll
    for (int m = 0; m < 4; m++)
#pragma unroll
      for (int n = 0; n < 4; n++)
        acc[m][n] = __builtin_amdgcn_mfma_f32_16x16x32_bf16(A2[m], B1[n], acc[m][n], 0, 0, 0);
    __builtin_amdgcn_s_setprio(0);
    // all reads of this buffer are now issued; drain so phase-4 staging can't race
    asm volatile("s_waitcnt lgkmcnt(0)" ::: "memory");
    __builtin_amdgcn_s_barrier();

    // -- phase 4: stage tile t+2 into this (fully consumed) buffer; mfma(m4-7, ks1)
    if (t + 2 < TOT) STAGE(c, t + 2);
    __builtin_amdgcn_s_barrier();
    __builtin_amdgcn_s_setprio(1);
#pragma unroll
    for (int m = 0; m < 4; m++)
#pragma unroll
      for (int n = 0; n < 4; n++)
        acc[m + 4][n] = __builtin_amdgcn_mfma_f32_16x16x32_bf16(A3[m], B1[n], acc[m + 4][n], 0, 0, 0);
    __builtin_amdgcn_s_setprio(0);
    if (t + 2 < TOT) {
      asm volatile("s_waitcnt vmcnt(8)" ::: "memory");  // tile t+1 landed, t+2 in flight
    } else if (t + 1 < TOT) {
      asm volatile("s_waitcnt vmcnt(0)" ::: "memory");  // last prefetched tile landed
    }
    __builtin_amdgcn_s_barrier();

    // ---------------- per-M-tile epilogue (uniform branch) ----------------
    if ((t & (NT - 1)) == NT - 1) {
      const int rW = row0 + (t >> LNT) * 256 + wr * 128;
      const int cW = col0 + wc * 64;
      if constexpr (MODE == 0) {
        if (col0 >= 1024) {
          // V third -> vT[((w*16+h)*32+d)*64 + tok], 4 consecutive toks per store
#pragma unroll
          for (int m = 0; m < 8; m++) {
            const int rbase = rW + m * 16 + quad * 4;
            const int w_ = rbase >> 6, tokb = rbase & 63;
#pragma unroll
            for (int n = 0; n < 4; n++) {
              const int col = cW + n * 16 + l15;
              const float bv = bias[col];
              const int cg = col - 1024;
              const int head = cg >> 5, d = cg & 31;
              short pk[4];
#pragma unroll
              for (int r = 0; r < 4; r++) pk[r] = f2bfbits(acc[m][n][r] + bv);
              *(uint2*)(out2 + ((long)(w_ * 16 + head) * 32 + d) * 64 + tokb) =
                  *(const uint2*)pk;
            }
          }
        } else {
#pragma unroll
          for (int m = 0; m < 8; m++)
#pragma unroll
            for (int n = 0; n < 4; n++) {
              const int col = cW + n * 16 + l15;
              const float bv = bias[col];
#pragma unroll
              for (int r = 0; r < 4; r++) {
                const int row = rW + m * 16 + quad * 4 + r;
                ((short*)outv)[(long)row * 1024 + col] = f2bfbits(acc[m][n][r] + bv);
              }
            }
        }
      } else {
#pragma unroll
        for (int m = 0; m < 8; m++)
#pragma unroll
          for (int n = 0; n < 4; n++) {
            const int col = cW + n * 16 + l15;
            const float bv = bias[col];
#pragma unroll
            for (int r = 0; r < 4; r++) {
              const int row = rW + m * 16 + quad * 4 + r;
              float v = acc[m][n][r] + bv;
              if constexpr (MODE == 1) {
                const int n_ = row & 63, wiB = row >> 6;
                const int wi = wiB & 63, bb = wiB >> 6;
                const int p = (((wi >> 3) << 3) + (n_ >> 3) + 4) & 63;
                const int qq = (((wi & 7) << 3) + (n_ & 7) + 4) & 63;
                const long dst = ((long)bb * 4096 + p * 64 + qq) * 512 + col;
                ((float*)outv)[dst] = v + aux[dst];
              } else if constexpr (MODE == 2) {
                const float g = 0.5f * v * (1.0f + erff(v * 0.70710678118654752f));
                ((short*)outv)[(long)row * (GN * 256) + col] = f2bfbits(g);
              } else {
                const long ix = (long)row * (GN * 256) + col;
                ((float*)outv)[ix] = v + aux[ix];
              }
            }
          }
      }
      if (t + 1 < TOT) {
#pragma unroll
        for (int m = 0; m < 8; m++)
#pragma unroll
          for (int n = 0; n < 4; n++) acc[m][n] = (f32x4){0.f, 0.f, 0.f, 0.f};
      }
    }
  }
#undef STAGE
}

// ---------------- Windowed attention: one wave per (window, head) ----------
__global__ __launch_bounds__(256)
void attn(const short* __restrict__ qk, const short* __restrict__ vT,
          const short* __restrict__ bm, short* __restrict__ o) {
  __shared__ short P[4][64 * 72];
  const int lane = threadIdx.x & 63, wave = threadIdx.x >> 6;
  const int l15 = lane & 15, quad = lane >> 4;
  const int w = blockIdx.x;                 // 0..1023  (b*64 + wi)
  const int hh = blockIdx.y * 4 + wave;     // head 0..15
  const int wi = w & 63;
  const short* base = qk + (long)w * 64 * 1024;

  short8 qf[4], kf[4];
#pragma unroll
  for (int mt = 0; mt < 4; mt++) {
    const int tq = mt * 16 + l15;
    qf[mt] = *(const short8*)(base + tq * 1024 + hh * 32 + quad * 8);
    kf[mt] = *(const short8*)(base + tq * 1024 + 512 + hh * 32 + quad * 8);
  }
  f32x4 S[4][4];
#pragma unroll
  for (int i = 0; i < 4; i++)
#pragma unroll
    for (int j = 0; j < 4; j++) S[i][j] = (f32x4){0.f, 0.f, 0.f, 0.f};
#pragma unroll
  for (int mt = 0; mt < 4; mt++)
#pragma unroll
    for (int nt = 0; nt < 4; nt++)
      S[mt][nt] = __builtin_amdgcn_mfma_f32_16x16x32_bf16(qf[mt], kf[nt], S[mt][nt], 0, 0, 0);

  // scale + combined bias/mask + row softmax; P -> LDS (bf16, stride 72)
  // P is wave-private: no cross-wave barrier needed (compiler orders same-wave
  // ds_write -> ds_read via lgkmcnt).
  short* pw = P[wave];
  const short* bmp = bm + (long)(wi * 16 + hh) * 4096;
  const float scale = 0.17677669529663687f;  // 32^-0.5
#pragma unroll
  for (int mt = 0; mt < 4; mt++) {
#pragma unroll
    for (int reg = 0; reg < 4; reg++) {
      const int m = mt * 16 + quad * 4 + reg;
      float vals[4];
#pragma unroll
      for (int nt = 0; nt < 4; nt++)
        vals[nt] = S[mt][nt][reg] * scale + bfbits2f(bmp[m * 64 + nt * 16 + l15]);
      float mx = fmaxf(fmaxf(vals[0], vals[1]), fmaxf(vals[2], vals[3]));
#pragma unroll
      for (int o_ = 1; o_ < 16; o_ <<= 1) mx = fmaxf(mx, __shfl_xor(mx, o_, 64));
      float e[4], sum = 0.f;
#pragma unroll
      for (int nt = 0; nt < 4; nt++) { e[nt] = __expf(vals[nt] - mx); sum += e[nt]; }
#pragma unroll
      for (int o_ = 1; o_ < 16; o_ <<= 1) sum += __shfl_xor(sum, o_, 64);
      const float inv = 1.0f / sum;
#pragma unroll
      for (int nt = 0; nt < 4; nt++)
        pw[m * 72 + nt * 16 + l15] = f2bfbits(e[nt] * inv);
    }
  }

  // O = P @ V : P from LDS (A-layout), V^T from global (B-layout, vector loads)
  const short* vbase = vT + (long)(w * 16 + hh) * 2048;
  f32x4 O[4][2];
#pragma unroll
  for (int i = 0; i < 4; i++)
#pragma unroll
    for (int j = 0; j < 2; j++) O[i][j] = (f32x4){0.f, 0.f, 0.f, 0.f};
#pragma unroll
  for (int ks = 0; ks < 2; ks++) {
    short8 vf[2];
#pragma unroll
    for (int nt = 0; nt < 2; nt++)
      vf[nt] = *(const short8*)(vbase + (nt * 16 + l15) * 64 + ks * 32 + quad * 8);
#pragma unroll
    for (int mt = 0; mt < 4; mt++) {
      short8 pf = *(const short8*)(pw + (mt * 16 + l15) * 72 + ks * 32 + quad * 8);
#pragma unroll
      for (int nt = 0; nt < 2; nt++)
        O[mt][nt] = __builtin_amdgcn_mfma_f32_16x16x32_bf16(pf, vf[nt], O[mt][nt], 0, 0, 0);
    }
  }
#pragma unroll
  for (int mt = 0; mt < 4; mt++)
#pragma unroll
    for (int nt = 0; nt < 2; nt++)
#pragma unroll
      for (int reg = 0; reg < 4; reg++) {
        const int t = mt * 16 + quad * 4 + reg;
        const int d = nt * 16 + l15;
        o[((long)w * 64 + t) * 512 + hh * 32 + d] = f2bfbits(O[mt][nt][reg]);
      }
}

extern "C" void kernel_launch(void* const* d_in, const int* in_sizes, int n_in,
                              void* d_out, int out_size, void* d_ws, size_t ws_size,
                              hipStream_t stream) {
  const float* x      = (const float*)d_in[0];
  const float* qkv_w  = (const float*)d_in[1];
  const float* qkv_b  = (const float*)d_in[2];
  const float* proj_w = (const float*)d_in[3];
  const float* proj_b = (const float*)d_in[4];
  const float* n1w    = (const float*)d_in[5];
  const float* n1b    = (const float*)d_in[6];
  const float* n2w    = (const float*)d_in[7];
  const float* n2b    = (const float*)d_in[8];
  const float* fc1_w  = (const float*)d_in[9];
  const float* fc1_b  = (const float*)d_in[10];
  const float* fc2_w  = (const float*)d_in[11];
  const float* fc2_b  = (const float*)d_in[12];
  const float* table  = (const float*)d_in[13];
  const int*   idx    = (const int*)d_in[14];
  const float* mask   = (const float*)d_in[15];

  char* ws = (char*)d_ws;
  // Workspace (peak 273 MiB):
  //   [0, 8Mi):    bf16 weights
  //   [8Mi,17Mi):  bm combined bias+mask (8.4 MB)
  //   [17Mi,81Mi): h (LN1) -> o (attn out) -> xn2 (LN2)   [bf16 64 MiB]
  //   [81Mi,209Mi): qk (bf16, Q|K stride 1024) -> h2 chunk (32768x2048 bf16)
  //   [209Mi,273Mi): vT (bf16, [1024][16][32][64])
  const long MB = 1048576L;
  short* wq  = (short*)(ws);
  short* wp  = wq + 786432;
  short* w1  = wp + 262144;
  short* w2  = w1 + 1048576;
  short* bm  = (short*)(ws + 8 * MB);
  short* h   = (short*)(ws + 17 * MB);
  short* o   = h;
  short* xn2 = h;
  short* qk  = (short*)(ws + 81 * MB);
  short* h2c = qk;
  short* vT  = (short*)(ws + 209 * MB);
  float* out = (float*)d_out;  // holds x2 (fp32) until fc2 overwrites

  f2bf<<<768, 256, 0, stream>>>(qkv_w, wq, 786432);
  f2bf<<<256, 256, 0, stream>>>(proj_w, wp, 262144);
  f2bf<<<1024, 256, 0, stream>>>(fc1_w, w1, 1048576);
  f2bf<<<1024, 256, 0, stream>>>(fc2_w, w2, 1048576);
  bm_build<<<dim3(64, 16), 256, 0, stream>>>(table, idx, mask, bm);

  ln1_win<<<16384, 256, 0, stream>>>(x, n1w, n1b, h);
  // QKV: M-tiles 256, MTB=2 -> 768 blocks = 3 even rounds
  gemm256<0, 512, 6, 2><<<768, 512, 0, stream>>>(h, wq, qkv_b, nullptr, qk, vT);
  attn<<<dim3(1024, 4), 256, 0, stream>>>(qk, vT, bm, o);
  // proj: M-tiles 256, MTB=2 -> 256 blocks = 1 round
  gemm256<1, 512, 2, 2><<<256, 512, 0, stream>>>(o, wp, proj_b, x, out, nullptr);
  ln2_id<<<16384, 256, 0, stream>>>(out, n2w, n2b, xn2);
  for (int c = 0; c < 2; c++) {
    const long ro = (long)c * 32768;
    // fc1: M-tiles 128, MTB=4 -> 256 blocks = 1 round, 32-tile persistent loop
    gemm256<2, 512, 8, 4><<<256, 512, 0, stream>>>(
        xn2 + ro * 512, w1, fc1_b, nullptr, h2c, nullptr);
    // fc2: K=2048 (NT=32), MTB=1 -> 256 blocks = 1 round
    gemm256<3, 2048, 2, 1><<<256, 512, 0, stream>>>(
        h2c, w2, fc2_b, out + ro * 512, out + ro * 512, nullptr);
  }
}

// Round 3
// 991.120 us; speedup vs baseline: 1.1148x; 1.1148x over previous
//
#include <hip/hip_runtime.h>
#include <hip/hip_bf16.h>

typedef __attribute__((ext_vector_type(8))) short short8;
typedef __attribute__((ext_vector_type(4))) float f32x4;

__device__ __forceinline__ short f2bfbits(float f) {
  union { __hip_bfloat16 h; short s; } cvt;
  cvt.h = __float2bfloat16(f);
  return cvt.s;
}
__device__ __forceinline__ float bfbits2f(short bits) {
  union { unsigned int u; float f; } cvt;
  cvt.u = ((unsigned int)(unsigned short)bits) << 16;
  return cvt.f;
}

// Async global->LDS, 16 B per lane. LDS dest = wave-uniform base + lane*16.
__device__ __forceinline__ void gl_lds16(const short* g, short* l) {
  __builtin_amdgcn_global_load_lds(
      (__attribute__((address_space(1))) void*)(g),
      (__attribute__((address_space(3))) void*)(l), 16, 0, 0);
}

// ---------------- fp32 -> bf16 weight conversion ----------
__global__ __launch_bounds__(256)
void f2bf(const float* __restrict__ s, short* __restrict__ d, int n) {
  const int i = (blockIdx.x * 256 + threadIdx.x) * 4;
  if (i >= n) return;
  float4 v = *(const float4*)(s + i);
  short o[4] = {f2bfbits(v.x), f2bfbits(v.y), f2bfbits(v.z), f2bfbits(v.w)};
  *(uint2*)(d + i) = *(const uint2*)o;
}

// ---------------- combined rel-pos-bias + shift-mask table: bm[wi][h][m][n] bf16
__global__ __launch_bounds__(256)
void bm_build(const float* __restrict__ table, const int* __restrict__ idx,
              const float* __restrict__ mask, short* __restrict__ bm) {
  const int wi = blockIdx.x, hh = blockIdx.y;
  const int n = threadIdx.x & 63;
  const int m0 = (threadIdx.x >> 6) * 16;
#pragma unroll
  for (int mm = 0; mm < 16; mm++) {
    const int m = m0 + mm;
    const float t = table[idx[m * 64 + n] * 16 + hh];
    const float mk = mask[wi * 4096 + m * 64 + n];
    bm[((long)(wi * 16 + hh) * 64 + m) * 64 + n] = f2bfbits(t + mk);
  }
}

// ---------------- LN1 + roll(-4,-4) + window partition (fp32 in, bf16 out) --
__global__ __launch_bounds__(256)
void ln1_win(const float* __restrict__ x, const float* __restrict__ w,
             const float* __restrict__ b, short* __restrict__ h) {
  const int lane = threadIdx.x & 63;
  const int wv = threadIdx.x >> 6;
  const int t = blockIdx.x * 4 + wv;
  const int n = t & 63, wiB = t >> 6;
  const int wi = wiB & 63, bb = wiB >> 6;
  const int sr = (((wi >> 3) << 3) + (n >> 3) + 4) & 63;
  const int sc = (((wi & 7) << 3) + (n & 7) + 4) & 63;
  const float* xp = x + ((long)bb * 4096 + sr * 64 + sc) * 512 + lane * 8;
  float4 u0 = *(const float4*)(xp);
  float4 u1 = *(const float4*)(xp + 4);
  float v[8] = {u0.x, u0.y, u0.z, u0.w, u1.x, u1.y, u1.z, u1.w};
  float s = 0.f;
#pragma unroll
  for (int j = 0; j < 8; j++) s += v[j];
#pragma unroll
  for (int o = 1; o < 64; o <<= 1) s += __shfl_xor(s, o, 64);
  const float mean = s * (1.0f / 512.0f);
  float q = 0.f;
#pragma unroll
  for (int j = 0; j < 8; j++) { float d = v[j] - mean; q += d * d; }
#pragma unroll
  for (int o = 1; o < 64; o <<= 1) q += __shfl_xor(q, o, 64);
  const float rstd = rsqrtf(q * (1.0f / 512.0f) + 1e-5f);
  float4 w0 = *(const float4*)(w + lane * 8);
  float4 w1 = *(const float4*)(w + lane * 8 + 4);
  float4 b0 = *(const float4*)(b + lane * 8);
  float4 b1 = *(const float4*)(b + lane * 8 + 4);
  const float wv8[8] = {w0.x, w0.y, w0.z, w0.w, w1.x, w1.y, w1.z, w1.w};
  const float bv8[8] = {b0.x, b0.y, b0.z, b0.w, b1.x, b1.y, b1.z, b1.w};
  short outs[8];
#pragma unroll
  for (int j = 0; j < 8; j++)
    outs[j] = f2bfbits((v[j] - mean) * rstd * wv8[j] + bv8[j]);
  *(uint4*)(h + (long)t * 512 + lane * 8) = *(const uint4*)outs;
}

// ---------------- LN2 (identity layout, fp32 in, bf16 out) ----------------
__global__ __launch_bounds__(256)
void ln2_id(const float* __restrict__ x2, const float* __restrict__ w,
            const float* __restrict__ b, short* __restrict__ out) {
  const int lane = threadIdx.x & 63;
  const int wv = threadIdx.x >> 6;
  const long t = blockIdx.x * 4 + wv;
  const float* xp = x2 + t * 512 + lane * 8;
  float4 u0 = *(const float4*)(xp);
  float4 u1 = *(const float4*)(xp + 4);
  float v[8] = {u0.x, u0.y, u0.z, u0.w, u1.x, u1.y, u1.z, u1.w};
  float s = 0.f;
#pragma unroll
  for (int j = 0; j < 8; j++) s += v[j];
#pragma unroll
  for (int o = 1; o < 64; o <<= 1) s += __shfl_xor(s, o, 64);
  const float mean = s * (1.0f / 512.0f);
  float q = 0.f;
#pragma unroll
  for (int j = 0; j < 8; j++) { float d = v[j] - mean; q += d * d; }
#pragma unroll
  for (int o = 1; o < 64; o <<= 1) q += __shfl_xor(q, o, 64);
  const float rstd = rsqrtf(q * (1.0f / 512.0f) + 1e-5f);
  float4 w0 = *(const float4*)(w + lane * 8);
  float4 w1 = *(const float4*)(w + lane * 8 + 4);
  float4 b0 = *(const float4*)(b + lane * 8);
  float4 b1 = *(const float4*)(b + lane * 8 + 4);
  const float wv8[8] = {w0.x, w0.y, w0.z, w0.w, w1.x, w1.y, w1.z, w1.w};
  const float bv8[8] = {b0.x, b0.y, b0.z, b0.w, b1.x, b1.y, b1.z, b1.w};
  short outs[8];
#pragma unroll
  for (int j = 0; j < 8; j++)
    outs[j] = f2bfbits((v[j] - mean) * rstd * wv8[j] + bv8[j]);
  *(uint4*)(out + t * 512 + lane * 8) = *(const uint4*)outs;
}

// ---------------- 128x128 2-phase B^T GEMM, 2 blocks/CU -------------------
// out[M,N] = A[M,K] @ Bw[N,K]^T + epilogue.  256 threads = 4 waves (2M x 2N),
// per-wave 64x64 output (acc = 64 regs -> fits 2 blocks/CU), BK=64,
// double-buffered LDS (64 KiB -> 2 blocks/CU co-resident), staging via
// global_load_lds w/ pre-swizzled source (granule ^= row&7), counted vmcnt(8).
// Two co-resident blocks per CU form independent pipelines: one block's
// barrier/vmcnt stalls are covered by the other block's MFMA waves.
// MODE 0: +bias -> Q/K to qk (stride 1024); V third transposed to out2 vT
// MODE 1: +bias, window-reverse + roll(+4) scatter, + residual aux -> fp32
// MODE 2: +bias, exact GELU -> bf16
// MODE 3: +bias, + residual aux (fp32, row-major) -> fp32 (final out)
template <int MODE, int K, int GN>
__global__ __launch_bounds__(256, 2)
void gemm128(const short* __restrict__ A, const short* __restrict__ Bw,
             const float* __restrict__ bias, const float* __restrict__ aux,
             void* __restrict__ outv, short* __restrict__ out2) {
  __shared__ short lds[32768];  // [2][8192] A tiles, then [2][8192] B tiles
  constexpr int NT = K / 64;
  const int tid = threadIdx.x;
  const int lane = tid & 63, wave = tid >> 6;
  const int l15 = lane & 15, quad = lane >> 4;
  const int wr = wave >> 1, wc = wave & 1;

  // XCD-chunked bijective swizzle (grid always a multiple of 8 here).
  const int nwg = gridDim.x;
  const int chunk = nwg >> 3;
  const int wg = (blockIdx.x & 7) * chunk + (blockIdx.x >> 3);
  const int row0 = (wg / GN) * 128;
  const int col0 = (wg % GN) * 128;

  // staging source (pre-swizzled): LDS slot (row, g) holds global (row, g^(row&7))
  const int srow = lane >> 3;                 // = row & 7 for this lane's rows
  const int scol = ((lane & 7) ^ srow) * 8;   // swizzled source granule (shorts)
  const short* Ag = A + (long)(row0 + wave * 32 + srow) * K + scol;
  const short* Bg = Bw + (long)(col0 + wave * 32 + srow) * K + scol;
  short* ldsAw = lds + wave * 2048;           // + lane*16B added by HW
  short* ldsBw = lds + 16384 + wave * 2048;

  // LDS read bases: logical granule (ks*4+quad) -> fetch granule ^ (row&7)
  const int g0 = (quad ^ (l15 & 7)) * 8;          // ks=0
  const int g1 = ((quad ^ 4) ^ (l15 & 7)) * 8;    // ks=1
  const int aB0 = (wr * 64 + l15) * 64 + g0;
  const int aB1 = (wr * 64 + l15) * 64 + g1;
  const int bB0 = 16384 + (wc * 64 + l15) * 64 + g0;
  const int bB1 = 16384 + (wc * 64 + l15) * 64 + g1;

  f32x4 acc[4][4];
#pragma unroll
  for (int m = 0; m < 4; m++)
#pragma unroll
    for (int n = 0; n < 4; n++) acc[m][n] = (f32x4){0.f, 0.f, 0.f, 0.f};

#define STAGE(cOff, kt)                                               \
  {                                                                   \
    const short* a_ = Ag + (kt) * 64;                                 \
    const short* b_ = Bg + (kt) * 64;                                 \
    _Pragma("unroll") for (int i_ = 0; i_ < 4; i_++) {                \
      gl_lds16(a_ + (long)i_ * 8 * K, ldsAw + (cOff) + i_ * 512);     \
      gl_lds16(b_ + (long)i_ * 8 * K, ldsBw + (cOff) + i_ * 512);     \
    }                                                                 \
  }

  STAGE(0, 0);
  STAGE(8192, 1);
  asm volatile("s_waitcnt vmcnt(8)" ::: "memory");  // tile0 landed, tile1 in flight
  __builtin_amdgcn_s_barrier();

  for (int t = 0; t < NT; ++t) {
    const int c = (t & 1) << 13;  // buffer offset in shorts
    const short* pa0 = lds + c + aB0;
    const short* pa1 = lds + c + aB1;
    const short* pb0 = lds + c + bB0;
    const short* pb1 = lds + c + bB1;
    short8 A0[4], A1[4], B0[4], B1[4];

    // -- phase 1: read A,B @ks0; mfma(ks0)
#pragma unroll
    for (int n = 0; n < 4; n++) B0[n] = *(const short8*)(pb0 + n * 1024);
#pragma unroll
    for (int m = 0; m < 4; m++) A0[m] = *(const short8*)(pa0 + m * 1024);
    asm volatile("" ::: "memory");
    __builtin_amdgcn_s_barrier();
    __builtin_amdgcn_s_setprio(1);
#pragma unroll
    for (int m = 0; m < 4; m++)
#pragma unroll
      for (int n = 0; n < 4; n++)
        acc[m][n] = __builtin_amdgcn_mfma_f32_16x16x32_bf16(A0[m], B0[n], acc[m][n], 0, 0, 0);
    __builtin_amdgcn_s_setprio(0);
    __builtin_amdgcn_s_barrier();

    // -- phase 2: read A,B @ks1; drain LDS reads; stage tile t+2 into this
    //    (fully consumed) buffer; mfma(ks1); counted vmcnt.
#pragma unroll
    for (int m = 0; m < 4; m++) A1[m] = *(const short8*)(pa1 + m * 1024);
#pragma unroll
    for (int n = 0; n < 4; n++) B1[n] = *(const short8*)(pb1 + n * 1024);
    asm volatile("s_waitcnt lgkmcnt(0)" ::: "memory");  // my reads of buf c done
    __builtin_amdgcn_s_barrier();                       // ALL waves' reads done
    if (t + 2 < NT) STAGE(c, t + 2);
    __builtin_amdgcn_s_setprio(1);
#pragma unroll
    for (int m = 0; m < 4; m++)
#pragma unroll
      for (int n = 0; n < 4; n++)
        acc[m][n] = __builtin_amdgcn_mfma_f32_16x16x32_bf16(A1[m], B1[n], acc[m][n], 0, 0, 0);
    __builtin_amdgcn_s_setprio(0);
    if (t + 2 < NT) {
      asm volatile("s_waitcnt vmcnt(8)" ::: "memory");  // tile t+1 landed, t+2 in flight
    } else if (t + 1 < NT) {
      asm volatile("s_waitcnt vmcnt(0)" ::: "memory");  // last prefetched tile landed
    }
    __builtin_amdgcn_s_barrier();
  }
#undef STAGE

  // ---------------- epilogue ----------------
  const int rW = row0 + wr * 64;
  const int cW = col0 + wc * 64;
  if constexpr (MODE == 0) {
    if (col0 >= 1024) {
      // V third -> vT[((w*16+h)*32+d)*64 + tok], 4 consecutive toks per store
#pragma unroll
      for (int m = 0; m < 4; m++) {
        const int rbase = rW + m * 16 + quad * 4;
        const int w_ = rbase >> 6, tokb = rbase & 63;
#pragma unroll
        for (int n = 0; n < 4; n++) {
          const int col = cW + n * 16 + l15;
          const float bv = bias[col];
          const int cg = col - 1024;
          const int head = cg >> 5, d = cg & 31;
          short pk[4];
#pragma unroll
          for (int r = 0; r < 4; r++) pk[r] = f2bfbits(acc[m][n][r] + bv);
          *(uint2*)(out2 + ((long)(w_ * 16 + head) * 32 + d) * 64 + tokb) =
              *(const uint2*)pk;
        }
      }
    } else {
#pragma unroll
      for (int m = 0; m < 4; m++)
#pragma unroll
        for (int n = 0; n < 4; n++) {
          const int col = cW + n * 16 + l15;
          const float bv = bias[col];
#pragma unroll
          for (int r = 0; r < 4; r++) {
            const int row = rW + m * 16 + quad * 4 + r;
            ((short*)outv)[(long)row * 1024 + col] = f2bfbits(acc[m][n][r] + bv);
          }
        }
    }
  } else {
#pragma unroll
    for (int m = 0; m < 4; m++)
#pragma unroll
      for (int n = 0; n < 4; n++) {
        const int col = cW + n * 16 + l15;
        const float bv = bias[col];
#pragma unroll
        for (int r = 0; r < 4; r++) {
          const int row = rW + m * 16 + quad * 4 + r;
          float v = acc[m][n][r] + bv;
          if constexpr (MODE == 1) {
            const int n_ = row & 63, wiB = row >> 6;
            const int wi = wiB & 63, bb = wiB >> 6;
            const int p = (((wi >> 3) << 3) + (n_ >> 3) + 4) & 63;
            const int qq = (((wi & 7) << 3) + (n_ & 7) + 4) & 63;
            const long dst = ((long)bb * 4096 + p * 64 + qq) * 512 + col;
            ((float*)outv)[dst] = v + aux[dst];
          } else if constexpr (MODE == 2) {
            const float g = 0.5f * v * (1.0f + erff(v * 0.70710678118654752f));
            ((short*)outv)[(long)row * (GN * 128) + col] = f2bfbits(g);
          } else {
            const long ix = (long)row * (GN * 128) + col;
            ((float*)outv)[ix] = v + aux[ix];
          }
        }
      }
  }
}

// ---------------- Windowed attention: one wave per (window, head) ----------
__global__ __launch_bounds__(256)
void attn(const short* __restrict__ qk, const short* __restrict__ vT,
          const short* __restrict__ bm, short* __restrict__ o) {
  __shared__ short P[4][64 * 72];
  const int lane = threadIdx.x & 63, wave = threadIdx.x >> 6;
  const int l15 = lane & 15, quad = lane >> 4;
  const int w = blockIdx.x;                 // 0..1023  (b*64 + wi)
  const int hh = blockIdx.y * 4 + wave;     // head 0..15
  const int wi = w & 63;
  const short* base = qk + (long)w * 64 * 1024;

  short8 qf[4], kf[4];
#pragma unroll
  for (int mt = 0; mt < 4; mt++) {
    const int tq = mt * 16 + l15;
    qf[mt] = *(const short8*)(base + tq * 1024 + hh * 32 + quad * 8);
    kf[mt] = *(const short8*)(base + tq * 1024 + 512 + hh * 32 + quad * 8);
  }
  f32x4 S[4][4];
#pragma unroll
  for (int i = 0; i < 4; i++)
#pragma unroll
    for (int j = 0; j < 4; j++) S[i][j] = (f32x4){0.f, 0.f, 0.f, 0.f};
#pragma unroll
  for (int mt = 0; mt < 4; mt++)
#pragma unroll
    for (int nt = 0; nt < 4; nt++)
      S[mt][nt] = __builtin_amdgcn_mfma_f32_16x16x32_bf16(qf[mt], kf[nt], S[mt][nt], 0, 0, 0);

  // scale + combined bias/mask + row softmax; P -> LDS (bf16, stride 72)
  // P is wave-private: no cross-wave barrier needed (same-wave ds ordering
  // via lgkmcnt).
  short* pw = P[wave];
  const short* bmp = bm + (long)(wi * 16 + hh) * 4096;
  const float scale = 0.17677669529663687f;  // 32^-0.5
#pragma unroll
  for (int mt = 0; mt < 4; mt++) {
#pragma unroll
    for (int reg = 0; reg < 4; reg++) {
      const int m = mt * 16 + quad * 4 + reg;
      float vals[4];
#pragma unroll
      for (int nt = 0; nt < 4; nt++)
        vals[nt] = S[mt][nt][reg] * scale + bfbits2f(bmp[m * 64 + nt * 16 + l15]);
      float mx = fmaxf(fmaxf(vals[0], vals[1]), fmaxf(vals[2], vals[3]));
#pragma unroll
      for (int o_ = 1; o_ < 16; o_ <<= 1) mx = fmaxf(mx, __shfl_xor(mx, o_, 64));
      float e[4], sum = 0.f;
#pragma unroll
      for (int nt = 0; nt < 4; nt++) { e[nt] = __expf(vals[nt] - mx); sum += e[nt]; }
#pragma unroll
      for (int o_ = 1; o_ < 16; o_ <<= 1) sum += __shfl_xor(sum, o_, 64);
      const float inv = 1.0f / sum;
#pragma unroll
      for (int nt = 0; nt < 4; nt++)
        pw[m * 72 + nt * 16 + l15] = f2bfbits(e[nt] * inv);
    }
  }

  // O = P @ V : P from LDS (A-layout), V^T from global (B-layout, vector loads)
  const short* vbase = vT + (long)(w * 16 + hh) * 2048;
  f32x4 O[4][2];
#pragma unroll
  for (int i = 0; i < 4; i++)
#pragma unroll
    for (int j = 0; j < 2; j++) O[i][j] = (f32x4){0.f, 0.f, 0.f, 0.f};
#pragma unroll
  for (int ks = 0; ks < 2; ks++) {
    short8 vf[2];
#pragma unroll
    for (int nt = 0; nt < 2; nt++)
      vf[nt] = *(const short8*)(vbase + (nt * 16 + l15) * 64 + ks * 32 + quad * 8);
#pragma unroll
    for (int mt = 0; mt < 4; mt++) {
      short8 pf = *(const short8*)(pw + (mt * 16 + l15) * 72 + ks * 32 + quad * 8);
#pragma unroll
      for (int nt = 0; nt < 2; nt++)
        O[mt][nt] = __builtin_amdgcn_mfma_f32_16x16x32_bf16(pf, vf[nt], O[mt][nt], 0, 0, 0);
    }
  }
#pragma unroll
  for (int mt = 0; mt < 4; mt++)
#pragma unroll
    for (int nt = 0; nt < 2; nt++)
#pragma unroll
      for (int reg = 0; reg < 4; reg++) {
        const int t = mt * 16 + quad * 4 + reg;
        const int d = nt * 16 + l15;
        o[((long)w * 64 + t) * 512 + hh * 32 + d] = f2bfbits(O[mt][nt][reg]);
      }
}

extern "C" void kernel_launch(void* const* d_in, const int* in_sizes, int n_in,
                              void* d_out, int out_size, void* d_ws, size_t ws_size,
                              hipStream_t stream) {
  const float* x      = (const float*)d_in[0];
  const float* qkv_w  = (const float*)d_in[1];
  const float* qkv_b  = (const float*)d_in[2];
  const float* proj_w = (const float*)d_in[3];
  const float* proj_b = (const float*)d_in[4];
  const float* n1w    = (const float*)d_in[5];
  const float* n1b    = (const float*)d_in[6];
  const float* n2w    = (const float*)d_in[7];
  const float* n2b    = (const float*)d_in[8];
  const float* fc1_w  = (const float*)d_in[9];
  const float* fc1_b  = (const float*)d_in[10];
  const float* fc2_w  = (const float*)d_in[11];
  const float* fc2_b  = (const float*)d_in[12];
  const float* table  = (const float*)d_in[13];
  const int*   idx    = (const int*)d_in[14];
  const float* mask   = (const float*)d_in[15];

  char* ws = (char*)d_ws;
  // Workspace (peak 273 MiB):
  //   [0, 8Mi):    bf16 weights
  //   [8Mi,17Mi):  bm combined bias+mask (8.4 MB)
  //   [17Mi,81Mi): h (LN1) -> o (attn out) -> xn2 (LN2)   [bf16 64 MiB]
  //   [81Mi,209Mi): qk (bf16, Q|K stride 1024) -> h2 chunk (32768x2048 bf16)
  //   [209Mi,273Mi): vT (bf16, [1024][16][32][64])
  const long MB = 1048576L;
  short* wq  = (short*)(ws);
  short* wp  = wq + 786432;
  short* w1  = wp + 262144;
  short* w2  = w1 + 1048576;
  short* bm  = (short*)(ws + 8 * MB);
  short* h   = (short*)(ws + 17 * MB);
  short* o   = h;
  short* xn2 = h;
  short* qk  = (short*)(ws + 81 * MB);
  short* h2c = qk;
  short* vT  = (short*)(ws + 209 * MB);
  float* out = (float*)d_out;  // holds x2 (fp32) until fc2 overwrites

  f2bf<<<768, 256, 0, stream>>>(qkv_w, wq, 786432);
  f2bf<<<256, 256, 0, stream>>>(proj_w, wp, 262144);
  f2bf<<<1024, 256, 0, stream>>>(fc1_w, w1, 1048576);
  f2bf<<<1024, 256, 0, stream>>>(fc2_w, w2, 1048576);
  bm_build<<<dim3(64, 16), 256, 0, stream>>>(table, idx, mask, bm);

  ln1_win<<<16384, 256, 0, stream>>>(x, n1w, n1b, h);
  // QKV: (65536/128) x (1536/128) = 512 x 12 = 6144 blocks, 2/CU co-resident
  gemm128<0, 512, 12><<<6144, 256, 0, stream>>>(h, wq, qkv_b, nullptr, qk, vT);
  attn<<<dim3(1024, 4), 256, 0, stream>>>(qk, vT, bm, o);
  // proj: 512 x 4 = 2048 blocks
  gemm128<1, 512, 4><<<2048, 256, 0, stream>>>(o, wp, proj_b, x, out, nullptr);
  ln2_id<<<16384, 256, 0, stream>>>(out, n2w, n2b, xn2);
  for (int c = 0; c < 2; c++) {
    const long ro = (long)c * 32768;
    // fc1: (32768/128) x (2048/128) = 256 x 16 = 4096 blocks
    gemm128<2, 512, 16><<<4096, 256, 0, stream>>>(
        xn2 + ro * 512, w1, fc1_b, nullptr, h2c, nullptr);
    // fc2: K=2048 (NT=32), (32768/128) x (512/128) = 256 x 4 = 1024 blocks
    gemm128<3, 2048, 4><<<1024, 256, 0, stream>>>(
        h2c, w2, fc2_b, out + ro * 512, out + ro * 512, nullptr);
  }
}